// Round 3
// baseline (305.785 us; speedup 1.0000x reference)
//
#include <hip/hip_runtime.h>

#define B_ 8
#define S_ 2048
#define M_ 256
#define D_ 512
#define P_ 512
#define H_ 8

#define SCALE 0.044194173824159216f  // 1/sqrt(512)

typedef __attribute__((ext_vector_type(8))) short bf16x8;
typedef __attribute__((ext_vector_type(4))) float f32x4;

static __device__ __forceinline__ float bf2f(short u) {
  union { float f; unsigned int i; } x;
  x.i = ((unsigned int)(unsigned short)u) << 16;
  return x.f;
}
static __device__ __forceinline__ short f2bf(float f) {
  union { float f; unsigned int i; } x;
  x.f = f;
  unsigned int r = (x.i + 0x7FFFu + ((x.i >> 16) & 1u)) >> 16;
  return (short)r;
}

// async global->LDS, 16B per lane; lds base must be wave-uniform
static __device__ __forceinline__ void gll16(const short* g, short* l) {
  __builtin_amdgcn_global_load_lds(
      (const __attribute__((address_space(1))) void*)g,
      (__attribute__((address_space(3))) void*)l, 16, 0, 0);
}

#define LGKM_WAIT() asm volatile("s_waitcnt lgkmcnt(0)" ::: "memory")
#define VMLG_WAIT() asm volatile("s_waitcnt vmcnt(0) lgkmcnt(0)" ::: "memory")
#define RAW_BAR() do { asm volatile("" ::: "memory"); __builtin_amdgcn_s_barrier(); asm volatile("" ::: "memory"); } while (0)

// ---------------------------------------------------------------------------
// fused fp32 -> bf16 cast (RNE) for input_seq and memory_cells
// ---------------------------------------------------------------------------
__global__ __launch_bounds__(256) void cast_both(
    const float* __restrict__ inA, short* __restrict__ outA, int n4A,
    const float* __restrict__ inM, short* __restrict__ outM)
{
  int idx = blockIdx.x * 256 + threadIdx.x;
  const float* in = inA;
  short* out = outA;
  if (idx >= n4A) { idx -= n4A; in = inM; out = outM; }
  float4 v = ((const float4*)in)[idx];
  short o0 = f2bf(v.x), o1 = f2bf(v.y), o2 = f2bf(v.z), o3 = f2bf(v.w);
  uint2 pk;
  pk.x = (unsigned int)(unsigned short)o0 | ((unsigned int)(unsigned short)o1 << 16);
  pk.y = (unsigned int)(unsigned short)o2 | ((unsigned int)(unsigned short)o3 << 16);
  ((uint2*)out)[idx] = pk;
}

// ---------------------------------------------------------------------------
// merged weight transpose+cast for the 512x512 weights
// ---------------------------------------------------------------------------
__global__ __launch_bounds__(256) void wtrans_all(
    const float* __restrict__ Wk, const float* __restrict__ Wv,
    const float* __restrict__ Wq,
    short* __restrict__ WkT, short* __restrict__ WvT, short* __restrict__ WqT)
{
  __shared__ float tile[32][33];
  const int t = threadIdx.x, tx = t & 31, ty = t >> 5;
  const int z = blockIdx.z;
  const float* inp;
  short* outp;
  if (z == 0)      { inp = Wk; outp = WkT; }
  else if (z == 1) { inp = Wv; outp = WvT; }
  else             { inp = Wq + (size_t)(z - 2) * 512 * 512;
                     outp = WqT + (size_t)(z - 2) * 512 * 512; }
  const int n0 = blockIdx.x * 32, k0 = blockIdx.y * 32;
#pragma unroll
  for (int i = 0; i < 4; ++i)
    tile[ty + 8 * i][tx] = inp[(size_t)(k0 + ty + 8 * i) * 512 + n0 + tx];
  __syncthreads();
#pragma unroll
  for (int i = 0; i < 4; ++i)
    outp[(size_t)(n0 + ty + 8 * i) * 512 + k0 + tx] = f2bf(tile[tx][ty + 8 * i]);
}

// ---------------------------------------------------------------------------
// Wo transpose+cast: [4096 k][512 n] fp32 -> [512 n][4096 k] bf16
// ---------------------------------------------------------------------------
__global__ __launch_bounds__(256) void wtrans_wo(
    const float* __restrict__ in, short* __restrict__ out)
{
  __shared__ float tile[32][33];
  const int t = threadIdx.x, tx = t & 31, ty = t >> 5;
  const int n0 = blockIdx.x * 32, k0 = blockIdx.y * 32;
#pragma unroll
  for (int i = 0; i < 4; ++i)
    tile[ty + 8 * i][tx] = in[(size_t)(k0 + ty + 8 * i) * 512 + n0 + tx];
  __syncthreads();
#pragma unroll
  for (int i = 0; i < 4; ++i)
    out[(size_t)(n0 + ty + 8 * i) * 4096 + k0 + tx] = f2bf(tile[tx][ty + 8 * i]);
}

// ---------------------------------------------------------------------------
// 128x128 MFMA GEMM, BK=32, 2-barrier single-buffer K-loop. Used for
// MODE 1 (q projection) and MODE 5 (Wo split-K).
// ---------------------------------------------------------------------------
template<int MODE, int K, int N, int LDA, int LDB>
__global__ __launch_bounds__(256, 3) void gemm128(
    const short* __restrict__ Abase, const short* __restrict__ Bbase,
    const float* __restrict__ bias, void* __restrict__ Cv,
    const size_t aZ, const size_t bZ, const size_t cZ,
    float* __restrict__ Ls,
    const float* __restrict__ eselfp, const short* __restrict__ mvbp)
{
  __shared__ short As[4096];
  __shared__ short Bs[4096];
  const int t = threadIdx.x;
  const int w = t >> 6, lane = t & 63, qd = lane >> 4, ln = lane & 15;
  const int wm = (w & 1) * 64, wn = (w >> 1) * 64;

  const int n0 = blockIdx.x * 128;
  const int m0 = blockIdx.y * 128;
  const int z = blockIdx.z;
  const int bsel = z;

  const short* A  = Abase + (size_t)z * aZ;
  const short* Bp = Bbase + (size_t)bsel * bZ;

  const int rr = t >> 2, g0 = t & 3;
  const int gs0 = g0 ^ ((rr >> 1) & 3);
  const int gs1 = g0 ^ (((rr + 64) >> 1) & 3);
  const short* ga0 = A + (size_t)(m0 + rr) * LDA + gs0 * 8;
  const short* ga1 = A + (size_t)(m0 + rr + 64) * LDA + gs1 * 8;
  const short* gb0 = Bp + (size_t)(n0 + rr) * LDB + gs0 * 8;
  const short* gb1 = Bp + (size_t)(n0 + rr + 64) * LDB + gs1 * 8;

  int aoff[4], boff[4];
#pragma unroll
  for (int mt = 0; mt < 4; ++mt) {
    int r = wm + mt * 16 + ln;
    aoff[mt] = r * 32 + (qd ^ ((r >> 1) & 3)) * 8;
  }
#pragma unroll
  for (int nt = 0; nt < 4; ++nt) {
    int r = wn + nt * 16 + ln;
    boff[nt] = r * 32 + (qd ^ ((r >> 1) & 3)) * 8;
  }

  f32x4 acc[4][4];
#pragma unroll
  for (int mt = 0; mt < 4; ++mt)
#pragma unroll
    for (int nt = 0; nt < 4; ++nt) acc[mt][nt] = (f32x4){0.f, 0.f, 0.f, 0.f};

  for (int kc = 0; kc < K; kc += 32) {
    __syncthreads();
    gll16(ga0 + kc, &As[w * 512]);
    gll16(ga1 + kc, &As[2048 + w * 512]);
    gll16(gb0 + kc, &Bs[w * 512]);
    gll16(gb1 + kc, &Bs[2048 + w * 512]);
    __syncthreads();

    bf16x8 af[4], bfr[4];
#pragma unroll
    for (int mt = 0; mt < 4; ++mt) af[mt] = *(const bf16x8*)&As[aoff[mt]];
#pragma unroll
    for (int nt = 0; nt < 4; ++nt) bfr[nt] = *(const bf16x8*)&Bs[boff[nt]];
#pragma unroll
    for (int mt = 0; mt < 4; ++mt)
#pragma unroll
      for (int nt = 0; nt < 4; ++nt)
        acc[mt][nt] = __builtin_amdgcn_mfma_f32_16x16x32_bf16(af[mt], bfr[nt], acc[mt][nt], 0, 0, 0);
  }

  if constexpr (MODE == 5) {
#pragma unroll
    for (int nt = 0; nt < 4; ++nt) {
      const int col = n0 + wn + nt * 16 + ln;
#pragma unroll
      for (int mt = 0; mt < 4; ++mt)
#pragma unroll
        for (int r = 0; r < 4; ++r) {
          const int row = m0 + wm + mt * 16 + qd * 4 + r;
          ((float*)Cv)[(size_t)z * cZ + (size_t)row * N + col] = acc[mt][nt][r];
        }
    }
  } else {  // MODE 1
#pragma unroll
    for (int nt = 0; nt < 4; ++nt) {
      const int col = n0 + wn + nt * 16 + ln;
      const float bc = bias[512 * z + col];
#pragma unroll
      for (int mt = 0; mt < 4; ++mt)
#pragma unroll
        for (int r = 0; r < 4; ++r) {
          const int row = m0 + wm + mt * 16 + qd * 4 + r;
          const int bidx = row >> 8, ml = row & 255;
          ((short*)Cv)[((size_t)(bidx * H_ + z) * M_ + ml) * N + col] = f2bf(acc[mt][nt][r] + bc);
        }
    }
  }
}

// ---------------------------------------------------------------------------
// QK kernel: 256x256 tile, BK=64, 512 thr (8 waves 2Mx4N, wave tile 128x64).
// ONE barrier per K-tile; no explicit lgkm between reads and MFMA -- the
// compiler emits progressive counted lgkmcnt per MFMA, so kk1's LDS reads
// are serviced under kk0's MFMA issue window (reads/MFMA overlap, the
// round-2 structure forbade this and measured MfmaUtil 22%).
// Tile body: read kk0 (12 b128) | stage tile t+1 -> buf p^1 (8 gll16) |
// MFMA kk0 (32) | read kk1 (12) | MFMA kk1 (32) | vmcnt(0)+lgkm(0) | BAR.
// Race-freedom: stages only touch p^1 (read from t+1 onward, after the
// tile-end vmcnt(0)+BAR); the tile-end lgkm(0) before the single barrier
// guarantees every wave's reads of buf p completed before t+1 stages into
// p. Stage age at the drain is ~1 full tile -> near-zero stall.
// LDS swizzle unchanged: chunk c of row r at c^(r&7), staged via
// pre-swizzled global source; ds_read_b128 conflict-free (measured 0).
// Epilogue: exp + rowsum atomics + LDS repack + 16B coalesced stores.
// ---------------------------------------------------------------------------
template<int NKT>
__global__ __launch_bounds__(512, 2) void qk256(
    const short* __restrict__ Abase, const short* __restrict__ Bbase,
    short* __restrict__ Eb, float* __restrict__ Ls)
{
  __shared__ short lds[65536];   // A: 2buf x [2half][128][64] | B same at +32768
  const int t = threadIdx.x;
  const int w = t >> 6, lane = t & 63, qd = lane >> 4, ln = lane & 15;
  const int wr = w >> 2, wc = w & 3;
  const int b = blockIdx.x;                       // XCD pin: flat id % 8 == b
  const int n0 = blockIdx.y * 256, m0 = blockIdx.z * 256;

  const short* A  = Abase + (size_t)b * (2048 * 512) + (size_t)m0 * 512;
  const short* Bp = Bbase + (size_t)b * (2048 * 512) + (size_t)n0 * 512;

  // staging source map: linear LDS slot s <- global(row=s>>3, chunk=(s&7)^(row&7))
  const int s0 = w * 64 + lane, s1 = s0 + 512;
  const int sr0 = s0 >> 3, sc0 = ((s0 & 7) ^ (sr0 & 7)) * 8;
  const int sr1 = s1 >> 3, sc1 = ((s1 & 7) ^ (sr1 & 7)) * 8;
  auto stage = [&](const short* g, short* lbase) {
    gll16(g + (size_t)sr0 * 512 + sc0, lbase + w * 512);
    gll16(g + (size_t)sr1 * 512 + sc1, lbase + 4096 + w * 512);
  };

  const int cq0 = ((qd    ) ^ (ln & 7)) * 8;
  const int cq1 = ((4 + qd) ^ (ln & 7)) * 8;
  const int brow = (wc & 1) * 64;

  f32x4 acc[8][4];
#pragma unroll
  for (int i = 0; i < 8; ++i)
#pragma unroll
    for (int j = 0; j < 4; ++j) acc[i][j] = (f32x4){0.f, 0.f, 0.f, 0.f};

  // ---- prologue: stage tile0, drain, go
  stage(A,              &lds[0]);
  stage(A + 128 * 512,  &lds[8192]);
  stage(Bp,             &lds[32768]);
  stage(Bp + 128 * 512, &lds[32768 + 8192]);
  asm volatile("s_waitcnt vmcnt(0)" ::: "memory");
  __builtin_amdgcn_s_barrier();

#pragma unroll 1
  for (int kt = 0; kt < NKT; ++kt) {
    const int p = kt & 1;
    short* Ah = &lds[p * 16384 + wr * 8192];
    short* Bh = &lds[32768 + p * 16384 + (wc >> 1) * 8192];

    bf16x8 a0[8], b0[4];
#pragma unroll
    for (int j = 0; j < 4; ++j)
      b0[j] = *(const bf16x8*)&Bh[(brow + j * 16 + ln) * 64 + cq0];
#pragma unroll
    for (int mt = 0; mt < 8; ++mt)
      a0[mt] = *(const bf16x8*)&Ah[(mt * 16 + ln) * 64 + cq0];
    if (kt + 1 < NKT) {
      stage(A  + (size_t)(kt + 1) * 64,             &lds[(p ^ 1) * 16384]);
      stage(A  + 128 * 512 + (size_t)(kt + 1) * 64, &lds[(p ^ 1) * 16384 + 8192]);
      stage(Bp + (size_t)(kt + 1) * 64,             &lds[32768 + (p ^ 1) * 16384]);
      stage(Bp + 128 * 512 + (size_t)(kt + 1) * 64, &lds[32768 + (p ^ 1) * 16384 + 8192]);
    }
    __builtin_amdgcn_s_setprio(1);
#pragma unroll
    for (int mt = 0; mt < 8; ++mt)
#pragma unroll
      for (int j = 0; j < 4; ++j)
        acc[mt][j] = __builtin_amdgcn_mfma_f32_16x16x32_bf16(a0[mt], b0[j], acc[mt][j], 0, 0, 0);
    __builtin_amdgcn_s_setprio(0);

    bf16x8 a1[8], b1[4];
#pragma unroll
    for (int j = 0; j < 4; ++j)
      b1[j] = *(const bf16x8*)&Bh[(brow + j * 16 + ln) * 64 + cq1];
#pragma unroll
    for (int mt = 0; mt < 8; ++mt)
      a1[mt] = *(const bf16x8*)&Ah[(mt * 16 + ln) * 64 + cq1];
    __builtin_amdgcn_s_setprio(1);
#pragma unroll
    for (int mt = 0; mt < 8; ++mt)
#pragma unroll
      for (int j = 0; j < 4; ++j)
        acc[mt][j] = __builtin_amdgcn_mfma_f32_16x16x32_bf16(a1[mt], b1[j], acc[mt][j], 0, 0, 0);
    __builtin_amdgcn_s_setprio(0);

    VMLG_WAIT();
    RAW_BAR();
  }

  // ---- epilogue: exp, rowsum atomics, LDS repack, coalesced stores
#pragma unroll
  for (int i = 0; i < 8; ++i)
#pragma unroll
    for (int j = 0; j < 4; ++j)
#pragma unroll
      for (int r = 0; r < 4; ++r)
        acc[i][j][r] = __expf(acc[i][j][r] * SCALE);
#pragma unroll
  for (int i = 0; i < 8; ++i)
#pragma unroll
    for (int r = 0; r < 4; ++r) {
      float rs = acc[i][0][r] + acc[i][1][r] + acc[i][2][r] + acc[i][3][r];
      rs += __shfl_xor(rs, 1);
      rs += __shfl_xor(rs, 2);
      rs += __shfl_xor(rs, 4);
      rs += __shfl_xor(rs, 8);
      if (ln == 0) {
        const int row = m0 + wr * 128 + i * 16 + qd * 4 + r;
        atomicAdd(&Ls[(size_t)b * 2048 + row], rs);
      }
    }
  // repack: lds[row*256 + (col ^ ((row&7)<<3))] (shorts), row/col local
#pragma unroll
  for (int i = 0; i < 8; ++i)
#pragma unroll
    for (int j = 0; j < 4; ++j)
#pragma unroll
      for (int r = 0; r < 4; ++r) {
        const int row = wr * 128 + i * 16 + qd * 4 + r;
        const int col = wc * 64 + j * 16 + ln;
        lds[row * 256 + (col ^ ((row & 7) << 3))] = f2bf(acc[i][j][r]);
      }
  LGKM_WAIT();
  RAW_BAR();
  short* Cb = Eb + (size_t)b * 2048 * 2048;
#pragma unroll
  for (int it = 0; it < 16; ++it) {
    const int flat = it * 512 + t;
    const int row = flat >> 5, c = flat & 31;
    bf16x8 v = *(const bf16x8*)&lds[row * 256 + ((c ^ (row & 7)) * 8)];
    *(bf16x8*)(Cb + (size_t)(m0 + row) * 2048 + n0 + c * 8) = v;
  }
}

// ---------------------------------------------------------------------------
// PV kernel: 256x128 tile, BK=64, K=2048 (NKT=32), 512 thr. Wave grid
// changed 2Mx4N -> 4Mx2N (wave tile 64x64): halves A-fragment LDS traffic
// (each A row-quarter read by 2 waves instead of 4; 128 KB/tile vs 160),
// acc = 4x4. Same one-barrier-per-tile overlap structure as qk256.
// LDS 96 KiB: A 2buf x 16384 shorts, B 2buf x 8192.
// Epilogue: normalize + eself*mv, repack 256x128 through LDS, 16B stores.
// ---------------------------------------------------------------------------
template<int NKT>
__global__ __launch_bounds__(512, 2) void pv128(
    const short* __restrict__ Abase, const short* __restrict__ Bbase,
    short* __restrict__ valb, const float* __restrict__ Ls,
    const float* __restrict__ eselfp, const short* __restrict__ mvbp)
{
  __shared__ short lds[49152];
  const int t = threadIdx.x;
  const int w = t >> 6, lane = t & 63, qd = lane >> 4, ln = lane & 15;
  const int wr = w >> 1, wc = w & 1;              // 4M x 2N
  const int b = blockIdx.x;                       // XCD pin
  const int n0 = blockIdx.y * 128;
  const int bz = blockIdx.z;                      // head tile: m0 = bz*256
  const int m0 = bz * 256;

  const short* A  = Abase + (size_t)b * (2048 * 2048) + (size_t)m0 * 2048;
  const short* Bp = Bbase + (size_t)b * (512 * 2048) + (size_t)n0 * 2048;

  const int s0 = w * 64 + lane, s1 = s0 + 512;
  const int sr0 = s0 >> 3, sc0 = ((s0 & 7) ^ (sr0 & 7)) * 8;
  const int sr1 = s1 >> 3, sc1 = ((s1 & 7) ^ (sr1 & 7)) * 8;
  auto stage = [&](const short* g, short* lbase) {
    gll16(g + (size_t)sr0 * 2048 + sc0, lbase + w * 512);
    gll16(g + (size_t)sr1 * 2048 + sc1, lbase + 4096 + w * 512);
  };

  const int cq0 = ((qd    ) ^ (ln & 7)) * 8;
  const int cq1 = ((4 + qd) ^ (ln & 7)) * 8;

  f32x4 acc[4][4];
#pragma unroll
  for (int i = 0; i < 4; ++i)
#pragma unroll
    for (int j = 0; j < 4; ++j) acc[i][j] = (f32x4){0.f, 0.f, 0.f, 0.f};

  // ---- prologue
  stage(A,               &lds[0]);
  stage(A + 128 * 2048,  &lds[8192]);
  stage(Bp,              &lds[32768]);
  asm volatile("s_waitcnt vmcnt(0)" ::: "memory");
  __builtin_amdgcn_s_barrier();

#pragma unroll 1
  for (int kt = 0; kt < NKT; ++kt) {
    const int p = kt & 1;
    short* Ah = &lds[p * 16384 + (wr >> 1) * 8192 + (wr & 1) * 4096];
    short* Bh = &lds[32768 + p * 8192];

    bf16x8 a0[4], b0[4];
#pragma unroll
    for (int j = 0; j < 4; ++j)
      b0[j] = *(const bf16x8*)&Bh[(wc * 64 + j * 16 + ln) * 64 + cq0];
#pragma unroll
    for (int mt = 0; mt < 4; ++mt)
      a0[mt] = *(const bf16x8*)&Ah[(mt * 16 + ln) * 64 + cq0];
    if (kt + 1 < NKT) {
      stage(A  + (size_t)(kt + 1) * 64,              &lds[(p ^ 1) * 16384]);
      stage(A  + 128 * 2048 + (size_t)(kt + 1) * 64, &lds[(p ^ 1) * 16384 + 8192]);
      stage(Bp + (size_t)(kt + 1) * 64,              &lds[32768 + (p ^ 1) * 8192]);
    }
    __builtin_amdgcn_s_setprio(1);
#pragma unroll
    for (int mt = 0; mt < 4; ++mt)
#pragma unroll
      for (int j = 0; j < 4; ++j)
        acc[mt][j] = __builtin_amdgcn_mfma_f32_16x16x32_bf16(a0[mt], b0[j], acc[mt][j], 0, 0, 0);
    __builtin_amdgcn_s_setprio(0);

    bf16x8 a1[4], b1[4];
#pragma unroll
    for (int j = 0; j < 4; ++j)
      b1[j] = *(const bf16x8*)&Bh[(wc * 64 + j * 16 + ln) * 64 + cq1];
#pragma unroll
    for (int mt = 0; mt < 4; ++mt)
      a1[mt] = *(const bf16x8*)&Ah[(mt * 16 + ln) * 64 + cq1];
    __builtin_amdgcn_s_setprio(1);
#pragma unroll
    for (int mt = 0; mt < 4; ++mt)
#pragma unroll
      for (int j = 0; j < 4; ++j)
        acc[mt][j] = __builtin_amdgcn_mfma_f32_16x16x32_bf16(a1[mt], b1[j], acc[mt][j], 0, 0, 0);
    __builtin_amdgcn_s_setprio(0);

    VMLG_WAIT();
    RAW_BAR();
  }

  // ---- epilogue: normalize + self-attn term, LDS repack, coalesced stores
#pragma unroll
  for (int mt = 0; mt < 4; ++mt)
#pragma unroll
    for (int r = 0; r < 4; ++r) {
      const int row = wr * 64 + mt * 16 + qd * 4 + r;   // local row 0..255
      const float es  = eselfp[(size_t)b * 2048 + m0 + row];
      const float inv = 1.f / (es + Ls[(size_t)b * 2048 + m0 + row]);
      const short* mvr = mvbp + ((size_t)(b * 256 + row)) * 512;
#pragma unroll
      for (int j = 0; j < 4; ++j) {
        const int lcol = wc * 64 + j * 16 + ln;
        const float v = (acc[mt][j][r] + es * bf2f(mvr[n0 + lcol])) * inv;
        lds[row * 128 + (lcol ^ ((row & 7) << 3))] = f2bf(v);
      }
    }
  LGKM_WAIT();
  RAW_BAR();
  // out rows: valb[(b*256+row)*4096 + bz*512 + n0 + ...]
#pragma unroll
  for (int it = 0; it < 8; ++it) {
    const int flat = it * 512 + t;
    const int row = flat >> 4, c = flat & 15;
    bf16x8 v = *(const bf16x8*)&lds[row * 128 + ((c ^ (row & 7)) * 8)];
    *(bf16x8*)(valb + ((size_t)(b * 256 + row)) * 4096 + (size_t)bz * 512 + n0 + c * 8) = v;
  }
}

// ---------------------------------------------------------------------------
// merged K/V projection, BK=32, 2-barrier single-buffer (16 KB LDS).
// ---------------------------------------------------------------------------
template<bool TRANSV>
__global__ __launch_bounds__(256, 3) void proj_kv(
    const short* __restrict__ A,
    const short* __restrict__ WkT, const short* __restrict__ WvT,
    const float* __restrict__ bk, const float* __restrict__ bv,
    short* __restrict__ Ck, short* __restrict__ Cvv)
{
  __shared__ short Sh[8192];
  short* As  = Sh;
  short* Bks = Sh + 4096;
  short* Bvs = Sh + 6144;
  const int t = threadIdx.x;
  const int w = t >> 6, lane = t & 63, qd = lane >> 4, ln = lane & 15;
  const int n0 = blockIdx.x * 64, m0 = blockIdx.y * 128;
  const int wm = (w & 1) * 64, wn2 = (w >> 1) * 32;

  const int rr = t >> 2, g0 = t & 3;
  const int gs0 = g0 ^ ((rr >> 1) & 3);
  const int gs1 = g0 ^ (((rr + 64) >> 1) & 3);
  const short* ga0 = A + (size_t)(m0 + rr) * 512 + gs0 * 8;
  const short* ga1 = A + (size_t)(m0 + rr + 64) * 512 + gs1 * 8;
  const short* gbk = WkT + (size_t)(n0 + rr) * 512 + gs0 * 8;
  const short* gbv = WvT + (size_t)(n0 + rr) * 512 + gs0 * 8;

  int aoff[4], boff[2];
#pragma unroll
  for (int mt = 0; mt < 4; ++mt) {
    int r = wm + mt * 16 + ln;
    aoff[mt] = r * 32 + (qd ^ ((r >> 1) & 3)) * 8;
  }
#pragma unroll
  for (int nt = 0; nt < 2; ++nt) {
    int r = wn2 + nt * 16 + ln;
    boff[nt] = r * 32 + (qd ^ ((r >> 1) & 3)) * 8;
  }

  f32x4 accK[4][2], accV[4][2];
#pragma unroll
  for (int mt = 0; mt < 4; ++mt)
#pragma unroll
    for (int nt = 0; nt < 2; ++nt) {
      accK[mt][nt] = (f32x4){0.f, 0.f, 0.f, 0.f};
      accV[mt][nt] = (f32x4){0.f, 0.f, 0.f, 0.f};
    }

  for (int kc = 0; kc < 512; kc += 32) {
    __syncthreads();
    gll16(ga0 + kc, &As[w * 512]);
    gll16(ga1 + kc, &As[2048 + w * 512]);
    gll16(gbk + kc, &Bks[w * 512]);
    gll16(gbv + kc, &Bvs[w * 512]);
    __syncthreads();

    bf16x8 af[4], bkf[2], bvf[2];
#pragma unroll
    for (int mt = 0; mt < 4; ++mt) af[mt] = *(const bf16x8*)&As[aoff[mt]];
#pragma unroll
    for (int nt = 0; nt < 2; ++nt) {
      bkf[nt] = *(const bf16x8*)&Bks[boff[nt]];
      bvf[nt] = *(const bf16x8*)&Bvs[boff[nt]];
    }
#pragma unroll
    for (int mt = 0; mt < 4; ++mt)
#pragma unroll
      for (int nt = 0; nt < 2; ++nt) {
        accK[mt][nt] = __builtin_amdgcn_mfma_f32_16x16x32_bf16(af[mt], bkf[nt], accK[mt][nt], 0, 0, 0);
        accV[mt][nt] = __builtin_amdgcn_mfma_f32_16x16x32_bf16(af[mt], bvf[nt], accV[mt][nt], 0, 0, 0);
      }
  }

#pragma unroll
  for (int nt = 0; nt < 2; ++nt) {
    const int col = n0 + wn2 + nt * 16 + ln;
    const float bc = bk[col];
#pragma unroll
    for (int mt = 0; mt < 4; ++mt)
#pragma unroll
      for (int r = 0; r < 4; ++r) {
        const int row = m0 + wm + mt * 16 + qd * 4 + r;
        Ck[(size_t)row * 512 + col] = f2bf(accK[mt][nt][r] + bc);
      }
  }

  if constexpr (!TRANSV) {
#pragma unroll
    for (int nt = 0; nt < 2; ++nt) {
      const int col = n0 + wn2 + nt * 16 + ln;
      const float bc = bv[col];
#pragma unroll
      for (int mt = 0; mt < 4; ++mt)
#pragma unroll
        for (int r = 0; r < 4; ++r) {
          const int row = m0 + wm + mt * 16 + qd * 4 + r;
          Cvv[(size_t)row * 512 + col] = f2bf(accV[mt][nt][r] + bc);
        }
    }
  } else {
    __syncthreads();
    short* ep = &Sh[w * 1280];
    const int lr = lane >> 1, lc16 = (lane & 1) * 16;
#pragma unroll
    for (int pass = 0; pass < 2; ++pass) {
#pragma unroll
      for (int mh = 0; mh < 2; ++mh) {
        const int mt = pass * 2 + mh;
#pragma unroll
        for (int nt = 0; nt < 2; ++nt) {
          const float bc = bv[n0 + wn2 + nt * 16 + ln];
#pragma unroll
          for (int r = 0; r < 4; ++r)
            ep[(nt * 16 + ln) * 40 + mh * 16 + qd * 4 + r] = f2bf(accV[mt][nt][r] + bc);
        }
      }
      LGKM_WAIT();
      const int srow0 = m0 + wm + pass * 32;
      const int bidx = srow0 >> 11;
      const int sloc = (srow0 & 2047) + lc16;
      const int pcol = n0 + wn2 + lr;
      short* outp = Cvv + (size_t)bidx * P_ * S_ + (size_t)pcol * S_ + sloc;
      *(bf16x8*)outp = *(const bf16x8*)&ep[lr * 40 + lc16];
      *(bf16x8*)(outp + 8) = *(const bf16x8*)&ep[lr * 40 + lc16 + 8];
      LGKM_WAIT();
    }
  }
}

// ---------------------------------------------------------------------------
// split-K reduce for Wo: out = sum_z partial[z] + bo[col], fp32
// ---------------------------------------------------------------------------
__global__ __launch_bounds__(256) void reduce_wo(
    const float* __restrict__ partial, const float* __restrict__ bo,
    float* __restrict__ out)
{
  const int idx4 = blockIdx.x * 256 + threadIdx.x;
  float4 s = ((const float4*)bo)[idx4 & 127];
#pragma unroll
  for (int zz = 0; zz < 4; ++zz) {
    float4 p = ((const float4*)partial)[(size_t)zz * 262144 + idx4];
    s.x += p.x; s.y += p.y; s.z += p.z; s.w += p.w;
  }
  ((float4*)out)[idx4] = s;
}

// ---------------------------------------------------------------------------
// self-score + Ls zeroing
// ---------------------------------------------------------------------------
__global__ __launch_bounds__(256) void selfscore(
    const short* __restrict__ qb, const short* __restrict__ mkb,
    float* __restrict__ eself, float* __restrict__ Ls)
{
  const int z = blockIdx.x, t = threadIdx.x;
  const short* qr = qb + ((size_t)z * M_ + t) * P_;
  const short* mr = mkb + ((size_t)(z >> 3) * M_ + t) * P_;
  float s = 0.f;
#pragma unroll 8
  for (int c = 0; c < P_; c += 8) {
    bf16x8 qv = *(const bf16x8*)(qr + c);
    bf16x8 mv = *(const bf16x8*)(mr + c);
#pragma unroll
    for (int j = 0; j < 8; ++j) s += bf2f(qv[j]) * bf2f(mv[j]);
  }
  eself[(size_t)z * M_ + t] = __expf(s * SCALE);
  Ls[(size_t)z * M_ + t] = 0.f;
}

// ---------------------------------------------------------------------------
extern "C" void kernel_launch(void* const* d_in, const int* in_sizes, int n_in,
                              void* d_out, int out_size, void* d_ws, size_t ws_size,
                              hipStream_t stream) {
  const float* input_seq = (const float*)d_in[0];
  const float* memcells  = (const float*)d_in[1];
  const float* Wk = (const float*)d_in[2];
  const float* bk = (const float*)d_in[3];
  const float* Wv = (const float*)d_in[4];
  const float* bv = (const float*)d_in[5];
  const float* Wq = (const float*)d_in[6];
  const float* bq = (const float*)d_in[7];
  const float* Wo = (const float*)d_in[8];
  const float* bo = (const float*)d_in[9];
  float* out = (float*)d_out;

  short* ws = (short*)d_ws;
  size_t o = 0;
  short* valb = ws + o; o += (size_t)B_ * M_ * H_ * P_;      // 8388608
  short* WoT  = ws + o; o += (size_t)(H_ * P_) * P_;          // 2097152
  short* mvb  = ws + o; o += (size_t)B_ * M_ * P_;            // 1048576
  short* mkb  = ws + o; o += (size_t)B_ * M_ * P_;            // 1048576
  short* qb   = ws + o; o += (size_t)B_ * H_ * M_ * P_;       // 8388608
  short* ivT  = ws + o; o += (size_t)B_ * P_ * S_;            // 8388608
  short* ikb  = ws + o; o += (size_t)B_ * S_ * P_;            // 8388608
  float* partial = (float*)(ws + o); o += (size_t)B_ * H_ * M_ * P_;  // 16 MB
  float* eself = (float*)(ws + o); o += 2 * (size_t)B_ * H_ * M_;
  float* Ls    = (float*)(ws + o); o += 2 * (size_t)B_ * H_ * M_;
  short* region2 = ws + o;                                    // Eb region (64 MB)
  short* Ab  = region2;
  short* Mb  = Ab + (size_t)B_ * S_ * D_;
  short* WkT = Mb + (size_t)B_ * M_ * D_;
  short* WvT = WkT + (size_t)D_ * P_;
  short* WqT = WvT + (size_t)D_ * P_;
  short* Eb  = region2;   // overlaps the above (all dead before E is written)

  dim3 blk(256);

  const int n4A = B_ * S_ * D_ / 4;
  const int n4M = B_ * M_ * D_ / 4;
  cast_both<<<dim3((n4A + n4M) / 256), blk, 0, stream>>>(input_seq, Ab, n4A, memcells, Mb);
  wtrans_all<<<dim3(16, 16, 10), blk, 0, stream>>>(Wk, Wv, Wq, WkT, WvT, WqT);
  wtrans_wo<<<dim3(16, 128), blk, 0, stream>>>(Wo, WoT);

  proj_kv<true><<<dim3(8, 128), blk, 0, stream>>>(Ab, WkT, WvT, bk, bv, ikb, ivT);
  proj_kv<false><<<dim3(8, 16), blk, 0, stream>>>(Mb, WkT, WvT, bk, bv, mkb, mvb);

  // q projection: MODE 1, z = h
  gemm128<1, 512, 512, 512, 512><<<dim3(4, 16, 8), blk, 0, stream>>>(
      Mb, WqT, bq, qb, 0, (size_t)D_ * P_, 0, nullptr, nullptr, nullptr);

  // eself + zero Ls (before QK's atomics)
  selfscore<<<dim3(64), blk, 0, stream>>>(qb, mkb, eself, Ls);

  // E = exp(scale * q @ ik^T) + fused row-sum; per-batch 2048x2048, K=512
  qk256<8><<<dim3(8, 8, 8), dim3(512), 0, stream>>>(qb, ikb, Eb, Ls);

  // val = normalize(E @ iv + eself*mv), concat layout; per-batch 2048x512,
  // K=2048; BN=128 -> grid 256 blocks (full GPU)
  pv128<32><<<dim3(8, 4, 8), dim3(512), 0, stream>>>(Eb, ivT, valb, Ls, eself, mvb);

  // Wo: split-K=4 partials, then reduce+bias
  gemm128<5, 1024, 512, 4096, 4096><<<dim3(4, 16, 4), blk, 0, stream>>>(
      valb, WoT, nullptr, partial, 1024, 1024,
      (size_t)2048 * 512, nullptr, nullptr, nullptr);
  reduce_wo<<<dim3(1024), blk, 0, stream>>>(partial, bo, out);
}

// Round 4
// 300.544 us; speedup vs baseline: 1.0174x; 1.0174x over previous
//
#include <hip/hip_runtime.h>

#define B_ 8
#define S_ 2048
#define M_ 256
#define D_ 512
#define P_ 512
#define H_ 8

#define SCALE 0.044194173824159216f  // 1/sqrt(512)

typedef __attribute__((ext_vector_type(8))) short bf16x8;
typedef __attribute__((ext_vector_type(4))) float f32x4;

static __device__ __forceinline__ float bf2f(short u) {
  union { float f; unsigned int i; } x;
  x.i = ((unsigned int)(unsigned short)u) << 16;
  return x.f;
}
static __device__ __forceinline__ short f2bf(float f) {
  union { float f; unsigned int i; } x;
  x.f = f;
  unsigned int r = (x.i + 0x7FFFu + ((x.i >> 16) & 1u)) >> 16;
  return (short)r;
}

// async global->LDS, 16B per lane; lds base must be wave-uniform
static __device__ __forceinline__ void gll16(const short* g, short* l) {
  __builtin_amdgcn_global_load_lds(
      (const __attribute__((address_space(1))) void*)g,
      (__attribute__((address_space(3))) void*)l, 16, 0, 0);
}

#define LGKM_WAIT() asm volatile("s_waitcnt lgkmcnt(0)" ::: "memory")
#define RAW_BAR() do { asm volatile("" ::: "memory"); __builtin_amdgcn_s_barrier(); asm volatile("" ::: "memory"); } while (0)

// ---------------------------------------------------------------------------
// fused fp32 -> bf16 cast (RNE) for input_seq and memory_cells
// ---------------------------------------------------------------------------
__global__ __launch_bounds__(256) void cast_both(
    const float* __restrict__ inA, short* __restrict__ outA, int n4A,
    const float* __restrict__ inM, short* __restrict__ outM)
{
  int idx = blockIdx.x * 256 + threadIdx.x;
  const float* in = inA;
  short* out = outA;
  if (idx >= n4A) { idx -= n4A; in = inM; out = outM; }
  float4 v = ((const float4*)in)[idx];
  short o0 = f2bf(v.x), o1 = f2bf(v.y), o2 = f2bf(v.z), o3 = f2bf(v.w);
  uint2 pk;
  pk.x = (unsigned int)(unsigned short)o0 | ((unsigned int)(unsigned short)o1 << 16);
  pk.y = (unsigned int)(unsigned short)o2 | ((unsigned int)(unsigned short)o3 << 16);
  ((uint2*)out)[idx] = pk;
}

// ---------------------------------------------------------------------------
// merged weight transpose+cast for the 512x512 weights
// ---------------------------------------------------------------------------
__global__ __launch_bounds__(256) void wtrans_all(
    const float* __restrict__ Wk, const float* __restrict__ Wv,
    const float* __restrict__ Wq,
    short* __restrict__ WkT, short* __restrict__ WvT, short* __restrict__ WqT)
{
  __shared__ float tile[32][33];
  const int t = threadIdx.x, tx = t & 31, ty = t >> 5;
  const int z = blockIdx.z;
  const float* inp;
  short* outp;
  if (z == 0)      { inp = Wk; outp = WkT; }
  else if (z == 1) { inp = Wv; outp = WvT; }
  else             { inp = Wq + (size_t)(z - 2) * 512 * 512;
                     outp = WqT + (size_t)(z - 2) * 512 * 512; }
  const int n0 = blockIdx.x * 32, k0 = blockIdx.y * 32;
#pragma unroll
  for (int i = 0; i < 4; ++i)
    tile[ty + 8 * i][tx] = inp[(size_t)(k0 + ty + 8 * i) * 512 + n0 + tx];
  __syncthreads();
#pragma unroll
  for (int i = 0; i < 4; ++i)
    outp[(size_t)(n0 + ty + 8 * i) * 512 + k0 + tx] = f2bf(tile[tx][ty + 8 * i]);
}

// ---------------------------------------------------------------------------
// Wo transpose+cast: [4096 k][512 n] fp32 -> [512 n][4096 k] bf16
// ---------------------------------------------------------------------------
__global__ __launch_bounds__(256) void wtrans_wo(
    const float* __restrict__ in, short* __restrict__ out)
{
  __shared__ float tile[32][33];
  const int t = threadIdx.x, tx = t & 31, ty = t >> 5;
  const int n0 = blockIdx.x * 32, k0 = blockIdx.y * 32;
#pragma unroll
  for (int i = 0; i < 4; ++i)
    tile[ty + 8 * i][tx] = in[(size_t)(k0 + ty + 8 * i) * 512 + n0 + tx];
  __syncthreads();
#pragma unroll
  for (int i = 0; i < 4; ++i)
    out[(size_t)(n0 + ty + 8 * i) * 4096 + k0 + tx] = f2bf(tile[tx][ty + 8 * i]);
}

// ---------------------------------------------------------------------------
// 128x128 MFMA GEMM, BK=32, 2-barrier single-buffer K-loop. Used for
// MODE 1 (q projection) and MODE 5 (Wo split-K).
// ---------------------------------------------------------------------------
template<int MODE, int K, int N, int LDA, int LDB>
__global__ __launch_bounds__(256, 3) void gemm128(
    const short* __restrict__ Abase, const short* __restrict__ Bbase,
    const float* __restrict__ bias, void* __restrict__ Cv,
    const size_t aZ, const size_t bZ, const size_t cZ,
    float* __restrict__ Ls,
    const float* __restrict__ eselfp, const short* __restrict__ mvbp)
{
  __shared__ short As[4096];
  __shared__ short Bs[4096];
  const int t = threadIdx.x;
  const int w = t >> 6, lane = t & 63, qd = lane >> 4, ln = lane & 15;
  const int wm = (w & 1) * 64, wn = (w >> 1) * 64;

  const int n0 = blockIdx.x * 128;
  const int m0 = blockIdx.y * 128;
  const int z = blockIdx.z;
  const int bsel = z;

  const short* A  = Abase + (size_t)z * aZ;
  const short* Bp = Bbase + (size_t)bsel * bZ;

  const int rr = t >> 2, g0 = t & 3;
  const int gs0 = g0 ^ ((rr >> 1) & 3);
  const int gs1 = g0 ^ (((rr + 64) >> 1) & 3);
  const short* ga0 = A + (size_t)(m0 + rr) * LDA + gs0 * 8;
  const short* ga1 = A + (size_t)(m0 + rr + 64) * LDA + gs1 * 8;
  const short* gb0 = Bp + (size_t)(n0 + rr) * LDB + gs0 * 8;
  const short* gb1 = Bp + (size_t)(n0 + rr + 64) * LDB + gs1 * 8;

  int aoff[4], boff[4];
#pragma unroll
  for (int mt = 0; mt < 4; ++mt) {
    int r = wm + mt * 16 + ln;
    aoff[mt] = r * 32 + (qd ^ ((r >> 1) & 3)) * 8;
  }
#pragma unroll
  for (int nt = 0; nt < 4; ++nt) {
    int r = wn + nt * 16 + ln;
    boff[nt] = r * 32 + (qd ^ ((r >> 1) & 3)) * 8;
  }

  f32x4 acc[4][4];
#pragma unroll
  for (int mt = 0; mt < 4; ++mt)
#pragma unroll
    for (int nt = 0; nt < 4; ++nt) acc[mt][nt] = (f32x4){0.f, 0.f, 0.f, 0.f};

  for (int kc = 0; kc < K; kc += 32) {
    __syncthreads();
    gll16(ga0 + kc, &As[w * 512]);
    gll16(ga1 + kc, &As[2048 + w * 512]);
    gll16(gb0 + kc, &Bs[w * 512]);
    gll16(gb1 + kc, &Bs[2048 + w * 512]);
    __syncthreads();

    bf16x8 af[4], bfr[4];
#pragma unroll
    for (int mt = 0; mt < 4; ++mt) af[mt] = *(const bf16x8*)&As[aoff[mt]];
#pragma unroll
    for (int nt = 0; nt < 4; ++nt) bfr[nt] = *(const bf16x8*)&Bs[boff[nt]];
#pragma unroll
    for (int mt = 0; mt < 4; ++mt)
#pragma unroll
      for (int nt = 0; nt < 4; ++nt)
        acc[mt][nt] = __builtin_amdgcn_mfma_f32_16x16x32_bf16(af[mt], bfr[nt], acc[mt][nt], 0, 0, 0);
  }

  if constexpr (MODE == 5) {
#pragma unroll
    for (int nt = 0; nt < 4; ++nt) {
      const int col = n0 + wn + nt * 16 + ln;
#pragma unroll
      for (int mt = 0; mt < 4; ++mt)
#pragma unroll
        for (int r = 0; r < 4; ++r) {
          const int row = m0 + wm + mt * 16 + qd * 4 + r;
          ((float*)Cv)[(size_t)z * cZ + (size_t)row * N + col] = acc[mt][nt][r];
        }
    }
  } else {  // MODE 1
#pragma unroll
    for (int nt = 0; nt < 4; ++nt) {
      const int col = n0 + wn + nt * 16 + ln;
      const float bc = bias[512 * z + col];
#pragma unroll
      for (int mt = 0; mt < 4; ++mt)
#pragma unroll
        for (int r = 0; r < 4; ++r) {
          const int row = m0 + wm + mt * 16 + qd * 4 + r;
          const int bidx = row >> 8, ml = row & 255;
          ((short*)Cv)[((size_t)(bidx * H_ + z) * M_ + ml) * N + col] = f2bf(acc[mt][nt][r] + bc);
        }
    }
  }
}

// ---------------------------------------------------------------------------
// QK kernel: 256x256 tile, BK=32, NKT=16, 512 thr (8 waves 2Mx4N, wave tile
// 128x64). RING-3 LDS pipeline (T3+T4): tile t reads buf[t%3], stages tile
// t+2 into buf[(t+2)%3] (4 gll16/thread), boundary wait = vmcnt(4) --
// drains only t+1's stages (issued a full tile ago, ~1500cy > HBM latency),
// keeps t+2's in flight. NEVER vmcnt(0) until the tail. One barrier/tile.
// Overwrite safety: tile t+1 stages into buf[t%3]; all reads of buf[t%3]
// are lgkm(0)-drained before the tile-t end barrier.
// Bank swizzle for 4-chunk rows (BK=32): chunk' = c ^ ((row>>1)&3).
// Fragment read (rows mt*16+ln, chunk qd): granule index (4*ln + qd^((ln>>1)
// &3)) mod 8 covers all 8 granules 2x per 16-lane group -> 2-way = free.
// Staged via inverse-swizzled GLOBAL source (rule 21), LDS dest linear.
// Epilogue: exp + rowsum atomics + LDS repack (128 KiB region, ring dead)
// + 16B coalesced stores.
// ---------------------------------------------------------------------------
template<int NKT>
__global__ __launch_bounds__(512, 2) void qk256(
    const short* __restrict__ Abase, const short* __restrict__ Bbase,
    short* __restrict__ Eb, float* __restrict__ Ls)
{
  __shared__ short lds[65536];   // ring: A 3x8192 @0, B 3x8192 @24576; repack uses all
  const int t = threadIdx.x;
  const int w = t >> 6, lane = t & 63, qd = lane >> 4, ln = lane & 15;
  const int wr = w >> 2, wc = w & 3;
  const int b = blockIdx.x;                       // XCD pin: flat id % 8 == b
  const int n0 = blockIdx.y * 256, m0 = blockIdx.z * 256;

  const short* A  = Abase + (size_t)b * (2048 * 512) + (size_t)m0 * 512;
  const short* Bp = Bbase + (size_t)b * (2048 * 512) + (size_t)n0 * 512;

  // staging source: LDS slot s holds global(row=s>>2, chunk=(s&3)^((row>>1)&3))
  const int srow = t >> 2;
  const int scol = ((t & 3) ^ ((srow >> 1) & 3)) * 8;
  const short* gsA = A  + (size_t)srow * 512 + scol;
  const short* gsB = Bp + (size_t)srow * 512 + scol;

  auto stageA = [&](const short* g, short* l) {
    gll16(g,             l + w * 512);          // rows 0..127
    gll16(g + 128 * 512, l + 4096 + w * 512);   // rows 128..255
  };
  auto stageB = [&](const short* g, short* l) {
    gll16(g,             l + w * 512);
    gll16(g + 128 * 512, l + 4096 + w * 512);
  };

  // fragment offsets: row stride 32 shorts, chunk' = qd ^ ((ln>>1)&3)
  const int fq = (qd ^ ((ln >> 1) & 3)) * 8;
  int aoff[8], boff[4];
#pragma unroll
  for (int mt = 0; mt < 8; ++mt) aoff[mt] = (mt * 16 + ln) * 32 + fq;
#pragma unroll
  for (int j = 0; j < 4; ++j)    boff[j]  = (j * 16 + ln) * 32 + fq;

  short* Ar = &lds[0];     short* An = &lds[8192];  short* Aw = &lds[16384];
  short* Br = &lds[24576]; short* Bn = &lds[32768]; short* Bw = &lds[40960];

  f32x4 acc[8][4];
#pragma unroll
  for (int i = 0; i < 8; ++i)
#pragma unroll
    for (int j = 0; j < 4; ++j) acc[i][j] = (f32x4){0.f, 0.f, 0.f, 0.f};

  // ---- prologue: stage tile0 -> buf0, tile1 -> buf1; wait tile0 only
  stageA(gsA,      Ar); stageB(gsB,      Br);
  stageA(gsA + 32, An); stageB(gsB + 32, Bn);
  asm volatile("s_waitcnt vmcnt(4)" ::: "memory");
  __builtin_amdgcn_s_barrier();

#pragma unroll 1
  for (int kt = 0; kt < NKT; ++kt) {
    short* Ah = Ar + wr * 4096;     // wave's 128-row half
    short* Bh = Br + wc * 2048;     // wave's 64-row window

    bf16x8 a[8], bfr[4];
#pragma unroll
    for (int j = 0; j < 4; ++j) bfr[j] = *(const bf16x8*)&Bh[boff[j]];
#pragma unroll
    for (int mt = 0; mt < 8; ++mt) a[mt] = *(const bf16x8*)&Ah[aoff[mt]];

    if (kt + 2 < NKT) {
      stageA(gsA + (size_t)(kt + 2) * 32, Aw);
      stageB(gsB + (size_t)(kt + 2) * 32, Bw);
    }

    __builtin_amdgcn_s_setprio(1);
#pragma unroll
    for (int mt = 0; mt < 8; ++mt)
#pragma unroll
      for (int j = 0; j < 4; ++j)
        acc[mt][j] = __builtin_amdgcn_mfma_f32_16x16x32_bf16(a[mt], bfr[j], acc[mt][j], 0, 0, 0);
    __builtin_amdgcn_s_setprio(0);

    if (kt + 2 < NKT) { asm volatile("s_waitcnt vmcnt(4) lgkmcnt(0)" ::: "memory"); }
    else              { asm volatile("s_waitcnt vmcnt(0) lgkmcnt(0)" ::: "memory"); }
    RAW_BAR();

    short* tA = Ar; Ar = An; An = Aw; Aw = tA;
    short* tB = Br; Br = Bn; Bn = Bw; Bw = tB;
  }

  // ---- epilogue: exp, rowsum atomics, LDS repack, coalesced stores
#pragma unroll
  for (int i = 0; i < 8; ++i)
#pragma unroll
    for (int j = 0; j < 4; ++j)
#pragma unroll
      for (int r = 0; r < 4; ++r)
        acc[i][j][r] = __expf(acc[i][j][r] * SCALE);
#pragma unroll
  for (int i = 0; i < 8; ++i)
#pragma unroll
    for (int r = 0; r < 4; ++r) {
      float rs = acc[i][0][r] + acc[i][1][r] + acc[i][2][r] + acc[i][3][r];
      rs += __shfl_xor(rs, 1);
      rs += __shfl_xor(rs, 2);
      rs += __shfl_xor(rs, 4);
      rs += __shfl_xor(rs, 8);
      if (ln == 0) {
        const int row = m0 + wr * 128 + i * 16 + qd * 4 + r;
        atomicAdd(&Ls[(size_t)b * 2048 + row], rs);
      }
    }
  // repack: lds[row*256 + (col ^ ((row&7)<<3))] (shorts), row/col local
#pragma unroll
  for (int i = 0; i < 8; ++i)
#pragma unroll
    for (int j = 0; j < 4; ++j)
#pragma unroll
      for (int r = 0; r < 4; ++r) {
        const int row = wr * 128 + i * 16 + qd * 4 + r;
        const int col = wc * 64 + j * 16 + ln;
        lds[row * 256 + (col ^ ((row & 7) << 3))] = f2bf(acc[i][j][r]);
      }
  LGKM_WAIT();
  RAW_BAR();
  short* Cb = Eb + (size_t)b * 2048 * 2048;
#pragma unroll
  for (int it = 0; it < 16; ++it) {
    const int flat = it * 512 + t;
    const int row = flat >> 5, c = flat & 31;
    bf16x8 v = *(const bf16x8*)&lds[row * 256 + ((c ^ (row & 7)) * 8)];
    *(bf16x8*)(Cb + (size_t)(m0 + row) * 2048 + n0 + c * 8) = v;
  }
}

// ---------------------------------------------------------------------------
// PV kernel: 256x128 tile, BK=64, K=2048 (NKT=32), 512 thr, wave grid 4Mx2N
// (wave tile 64x64). RING-3 LDS (144 KiB: A 3x16384 sh, B 3x8192 sh):
// tile t reads buf t%3, stages t+2 (6 gll16/thread), boundary vmcnt(6)
// counted -- never 0 until tail. One barrier/tile. Same swizzle as before
// (8-chunk rows, chunk' = c ^ (row&7)); reads conflict-free (measured 0).
// Epilogue: normalize + eself*mv, repack 256x128 through LDS, 16B stores.
// ---------------------------------------------------------------------------
template<int NKT>
__global__ __launch_bounds__(512, 2) void pv128(
    const short* __restrict__ Abase, const short* __restrict__ Bbase,
    short* __restrict__ valb, const float* __restrict__ Ls,
    const float* __restrict__ eselfp, const short* __restrict__ mvbp)
{
  __shared__ short lds[73728];   // A ring 3x16384 @0, B ring 3x8192 @49152
  const int t = threadIdx.x;
  const int w = t >> 6, lane = t & 63, qd = lane >> 4, ln = lane & 15;
  const int wr = w >> 1, wc = w & 1;              // 4M x 2N
  const int b = blockIdx.x;                       // XCD pin
  const int n0 = blockIdx.y * 128;
  const int bz = blockIdx.z;                      // head tile: m0 = bz*256
  const int m0 = bz * 256;

  const short* A  = Abase + (size_t)b * (2048 * 2048) + (size_t)m0 * 2048;
  const short* Bp = Bbase + (size_t)b * (512 * 2048) + (size_t)n0 * 2048;

  // staging source map (8-chunk rows): slot s <- global(row=s>>3, chunk=(s&7)^(row&7))
  const int s0 = w * 64 + lane, s1 = s0 + 512;
  const int sr0 = s0 >> 3, sc0 = ((s0 & 7) ^ (sr0 & 7)) * 8;
  const int sr1 = s1 >> 3, sc1 = ((s1 & 7) ^ (sr1 & 7)) * 8;
  auto stage = [&](const short* g, short* lbase) {   // 8192 shorts (128 rows)
    gll16(g + (size_t)sr0 * 2048 + sc0, lbase + w * 512);
    gll16(g + (size_t)sr1 * 2048 + sc1, lbase + 4096 + w * 512);
  };

  const int cq0 = ((qd    ) ^ (ln & 7)) * 8;
  const int cq1 = ((4 + qd) ^ (ln & 7)) * 8;

  short* Ar = &lds[0];     short* An = &lds[16384]; short* Aw = &lds[32768];
  short* Br = &lds[49152]; short* Bn = &lds[57344]; short* Bw = &lds[65536];

  f32x4 acc[4][4];
#pragma unroll
  for (int i = 0; i < 4; ++i)
#pragma unroll
    for (int j = 0; j < 4; ++j) acc[i][j] = (f32x4){0.f, 0.f, 0.f, 0.f};

  // ---- prologue: tile0 -> buf0, tile1 -> buf1; wait tile0 only
  stage(A,                   Ar);
  stage(A + 128 * 2048,      Ar + 8192);
  stage(Bp,                  Br);
  stage(A + 64,              An);
  stage(A + 128 * 2048 + 64, An + 8192);
  stage(Bp + 64,             Bn);
  asm volatile("s_waitcnt vmcnt(6)" ::: "memory");
  __builtin_amdgcn_s_barrier();

#pragma unroll 1
  for (int kt = 0; kt < NKT; ++kt) {
    short* Ah = Ar + (wr >> 1) * 8192 + (wr & 1) * 4096;   // wave's 64-row window
    short* Bh = Br;

    bf16x8 a0[4], b0[4];
#pragma unroll
    for (int j = 0; j < 4; ++j)
      b0[j] = *(const bf16x8*)&Bh[(wc * 64 + j * 16 + ln) * 64 + cq0];
#pragma unroll
    for (int mt = 0; mt < 4; ++mt)
      a0[mt] = *(const bf16x8*)&Ah[(mt * 16 + ln) * 64 + cq0];

    if (kt + 2 < NKT) {
      stage(A  + (size_t)(kt + 2) * 64,              Aw);
      stage(A  + 128 * 2048 + (size_t)(kt + 2) * 64, Aw + 8192);
      stage(Bp + (size_t)(kt + 2) * 64,              Bw);
    }

    __builtin_amdgcn_s_setprio(1);
#pragma unroll
    for (int mt = 0; mt < 4; ++mt)
#pragma unroll
      for (int j = 0; j < 4; ++j)
        acc[mt][j] = __builtin_amdgcn_mfma_f32_16x16x32_bf16(a0[mt], b0[j], acc[mt][j], 0, 0, 0);
    __builtin_amdgcn_s_setprio(0);

    bf16x8 a1[4], b1[4];
#pragma unroll
    for (int j = 0; j < 4; ++j)
      b1[j] = *(const bf16x8*)&Bh[(wc * 64 + j * 16 + ln) * 64 + cq1];
#pragma unroll
    for (int mt = 0; mt < 4; ++mt)
      a1[mt] = *(const bf16x8*)&Ah[(mt * 16 + ln) * 64 + cq1];
    __builtin_amdgcn_s_setprio(1);
#pragma unroll
    for (int mt = 0; mt < 4; ++mt)
#pragma unroll
      for (int j = 0; j < 4; ++j)
        acc[mt][j] = __builtin_amdgcn_mfma_f32_16x16x32_bf16(a1[mt], b1[j], acc[mt][j], 0, 0, 0);
    __builtin_amdgcn_s_setprio(0);

    if (kt + 2 < NKT) { asm volatile("s_waitcnt vmcnt(6) lgkmcnt(0)" ::: "memory"); }
    else              { asm volatile("s_waitcnt vmcnt(0) lgkmcnt(0)" ::: "memory"); }
    RAW_BAR();

    short* tA = Ar; Ar = An; An = Aw; Aw = tA;
    short* tB = Br; Br = Bn; Bn = Bw; Bw = tB;
  }

  // ---- epilogue: normalize + self-attn term, LDS repack, coalesced stores
#pragma unroll
  for (int mt = 0; mt < 4; ++mt)
#pragma unroll
    for (int r = 0; r < 4; ++r) {
      const int row = wr * 64 + mt * 16 + qd * 4 + r;   // local row 0..255
      const float es  = eselfp[(size_t)b * 2048 + m0 + row];
      const float inv = 1.f / (es + Ls[(size_t)b * 2048 + m0 + row]);
      const short* mvr = mvbp + ((size_t)(b * 256 + row)) * 512;
#pragma unroll
      for (int j = 0; j < 4; ++j) {
        const int lcol = wc * 64 + j * 16 + ln;
        const float v = (acc[mt][j][r] + es * bf2f(mvr[n0 + lcol])) * inv;
        lds[row * 128 + (lcol ^ ((row & 7) << 3))] = f2bf(v);
      }
    }
  LGKM_WAIT();
  RAW_BAR();
  // out rows: valb[(b*256+row)*4096 + bz*512 + n0 + ...]
#pragma unroll
  for (int it = 0; it < 8; ++it) {
    const int flat = it * 512 + t;
    const int row = flat >> 4, c = flat & 15;
    bf16x8 v = *(const bf16x8*)&lds[row * 128 + ((c ^ (row & 7)) * 8)];
    *(bf16x8*)(valb + ((size_t)(b * 256 + row)) * 4096 + (size_t)bz * 512 + n0 + c * 8) = v;
  }
}

// ---------------------------------------------------------------------------
// merged K/V projection, BK=32, 2-barrier single-buffer (16 KB LDS).
// ---------------------------------------------------------------------------
template<bool TRANSV>
__global__ __launch_bounds__(256, 3) void proj_kv(
    const short* __restrict__ A,
    const short* __restrict__ WkT, const short* __restrict__ WvT,
    const float* __restrict__ bk, const float* __restrict__ bv,
    short* __restrict__ Ck, short* __restrict__ Cvv)
{
  __shared__ short Sh[8192];
  short* As  = Sh;
  short* Bks = Sh + 4096;
  short* Bvs = Sh + 6144;
  const int t = threadIdx.x;
  const int w = t >> 6, lane = t & 63, qd = lane >> 4, ln = lane & 15;
  const int n0 = blockIdx.x * 64, m0 = blockIdx.y * 128;
  const int wm = (w & 1) * 64, wn2 = (w >> 1) * 32;

  const int rr = t >> 2, g0 = t & 3;
  const int gs0 = g0 ^ ((rr >> 1) & 3);
  const int gs1 = g0 ^ (((rr + 64) >> 1) & 3);
  const short* ga0 = A + (size_t)(m0 + rr) * 512 + gs0 * 8;
  const short* ga1 = A + (size_t)(m0 + rr + 64) * 512 + gs1 * 8;
  const short* gbk = WkT + (size_t)(n0 + rr) * 512 + gs0 * 8;
  const short* gbv = WvT + (size_t)(n0 + rr) * 512 + gs0 * 8;

  int aoff[4], boff[2];
#pragma unroll
  for (int mt = 0; mt < 4; ++mt) {
    int r = wm + mt * 16 + ln;
    aoff[mt] = r * 32 + (qd ^ ((r >> 1) & 3)) * 8;
  }
#pragma unroll
  for (int nt = 0; nt < 2; ++nt) {
    int r = wn2 + nt * 16 + ln;
    boff[nt] = r * 32 + (qd ^ ((r >> 1) & 3)) * 8;
  }

  f32x4 accK[4][2], accV[4][2];
#pragma unroll
  for (int mt = 0; mt < 4; ++mt)
#pragma unroll
    for (int nt = 0; nt < 2; ++nt) {
      accK[mt][nt] = (f32x4){0.f, 0.f, 0.f, 0.f};
      accV[mt][nt] = (f32x4){0.f, 0.f, 0.f, 0.f};
    }

  for (int kc = 0; kc < 512; kc += 32) {
    __syncthreads();
    gll16(ga0 + kc, &As[w * 512]);
    gll16(ga1 + kc, &As[2048 + w * 512]);
    gll16(gbk + kc, &Bks[w * 512]);
    gll16(gbv + kc, &Bvs[w * 512]);
    __syncthreads();

    bf16x8 af[4], bkf[2], bvf[2];
#pragma unroll
    for (int mt = 0; mt < 4; ++mt) af[mt] = *(const bf16x8*)&As[aoff[mt]];
#pragma unroll
    for (int nt = 0; nt < 2; ++nt) {
      bkf[nt] = *(const bf16x8*)&Bks[boff[nt]];
      bvf[nt] = *(const bf16x8*)&Bvs[boff[nt]];
    }
#pragma unroll
    for (int mt = 0; mt < 4; ++mt)
#pragma unroll
      for (int nt = 0; nt < 2; ++nt) {
        accK[mt][nt] = __builtin_amdgcn_mfma_f32_16x16x32_bf16(af[mt], bkf[nt], accK[mt][nt], 0, 0, 0);
        accV[mt][nt] = __builtin_amdgcn_mfma_f32_16x16x32_bf16(af[mt], bvf[nt], accV[mt][nt], 0, 0, 0);
      }
  }

#pragma unroll
  for (int nt = 0; nt < 2; ++nt) {
    const int col = n0 + wn2 + nt * 16 + ln;
    const float bc = bk[col];
#pragma unroll
    for (int mt = 0; mt < 4; ++mt)
#pragma unroll
      for (int r = 0; r < 4; ++r) {
        const int row = m0 + wm + mt * 16 + qd * 4 + r;
        Ck[(size_t)row * 512 + col] = f2bf(accK[mt][nt][r] + bc);
      }
  }

  if constexpr (!TRANSV) {
#pragma unroll
    for (int nt = 0; nt < 2; ++nt) {
      const int col = n0 + wn2 + nt * 16 + ln;
      const float bc = bv[col];
#pragma unroll
      for (int mt = 0; mt < 4; ++mt)
#pragma unroll
        for (int r = 0; r < 4; ++r) {
          const int row = m0 + wm + mt * 16 + qd * 4 + r;
          Cvv[(size_t)row * 512 + col] = f2bf(accV[mt][nt][r] + bc);
        }
    }
  } else {
    __syncthreads();
    short* ep = &Sh[w * 1280];
    const int lr = lane >> 1, lc16 = (lane & 1) * 16;
#pragma unroll
    for (int pass = 0; pass < 2; ++pass) {
#pragma unroll
      for (int mh = 0; mh < 2; ++mh) {
        const int mt = pass * 2 + mh;
#pragma unroll
        for (int nt = 0; nt < 2; ++nt) {
          const float bc = bv[n0 + wn2 + nt * 16 + ln];
#pragma unroll
          for (int r = 0; r < 4; ++r)
            ep[(nt * 16 + ln) * 40 + mh * 16 + qd * 4 + r] = f2bf(accV[mt][nt][r] + bc);
        }
      }
      LGKM_WAIT();
      const int srow0 = m0 + wm + pass * 32;
      const int bidx = srow0 >> 11;
      const int sloc = (srow0 & 2047) + lc16;
      const int pcol = n0 + wn2 + lr;
      short* outp = Cvv + (size_t)bidx * P_ * S_ + (size_t)pcol * S_ + sloc;
      *(bf16x8*)outp = *(const bf16x8*)&ep[lr * 40 + lc16];
      *(bf16x8*)(outp + 8) = *(const bf16x8*)&ep[lr * 40 + lc16 + 8];
      LGKM_WAIT();
    }
  }
}

// ---------------------------------------------------------------------------
// split-K reduce for Wo: out = sum_z partial[z] + bo[col], fp32
// ---------------------------------------------------------------------------
__global__ __launch_bounds__(256) void reduce_wo(
    const float* __restrict__ partial, const float* __restrict__ bo,
    float* __restrict__ out)
{
  const int idx4 = blockIdx.x * 256 + threadIdx.x;
  float4 s = ((const float4*)bo)[idx4 & 127];
#pragma unroll
  for (int zz = 0; zz < 4; ++zz) {
    float4 p = ((const float4*)partial)[(size_t)zz * 262144 + idx4];
    s.x += p.x; s.y += p.y; s.z += p.z; s.w += p.w;
  }
  ((float4*)out)[idx4] = s;
}

// ---------------------------------------------------------------------------
// self-score + Ls zeroing
// ---------------------------------------------------------------------------
__global__ __launch_bounds__(256) void selfscore(
    const short* __restrict__ qb, const short* __restrict__ mkb,
    float* __restrict__ eself, float* __restrict__ Ls)
{
  const int z = blockIdx.x, t = threadIdx.x;
  const short* qr = qb + ((size_t)z * M_ + t) * P_;
  const short* mr = mkb + ((size_t)(z >> 3) * M_ + t) * P_;
  float s = 0.f;
#pragma unroll 8
  for (int c = 0; c < P_; c += 8) {
    bf16x8 qv = *(const bf16x8*)(qr + c);
    bf16x8 mv = *(const bf16x8*)(mr + c);
#pragma unroll
    for (int j = 0; j < 8; ++j) s += bf2f(qv[j]) * bf2f(mv[j]);
  }
  eself[(size_t)z * M_ + t] = __expf(s * SCALE);
  Ls[(size_t)z * M_ + t] = 0.f;
}

// ---------------------------------------------------------------------------
extern "C" void kernel_launch(void* const* d_in, const int* in_sizes, int n_in,
                              void* d_out, int out_size, void* d_ws, size_t ws_size,
                              hipStream_t stream) {
  const float* input_seq = (const float*)d_in[0];
  const float* memcells  = (const float*)d_in[1];
  const float* Wk = (const float*)d_in[2];
  const float* bk = (const float*)d_in[3];
  const float* Wv = (const float*)d_in[4];
  const float* bv = (const float*)d_in[5];
  const float* Wq = (const float*)d_in[6];
  const float* bq = (const float*)d_in[7];
  const float* Wo = (const float*)d_in[8];
  const float* bo = (const float*)d_in[9];
  float* out = (float*)d_out;

  short* ws = (short*)d_ws;
  size_t o = 0;
  short* valb = ws + o; o += (size_t)B_ * M_ * H_ * P_;      // 8388608
  short* WoT  = ws + o; o += (size_t)(H_ * P_) * P_;          // 2097152
  short* mvb  = ws + o; o += (size_t)B_ * M_ * P_;            // 1048576
  short* mkb  = ws + o; o += (size_t)B_ * M_ * P_;            // 1048576
  short* qb   = ws + o; o += (size_t)B_ * H_ * M_ * P_;       // 8388608
  short* ivT  = ws + o; o += (size_t)B_ * P_ * S_;            // 8388608
  short* ikb  = ws + o; o += (size_t)B_ * S_ * P_;            // 8388608
  float* partial = (float*)(ws + o); o += (size_t)B_ * H_ * M_ * P_;  // 16 MB
  float* eself = (float*)(ws + o); o += 2 * (size_t)B_ * H_ * M_;
  float* Ls    = (float*)(ws + o); o += 2 * (size_t)B_ * H_ * M_;
  short* region2 = ws + o;                                    // Eb region (64 MB)
  short* Ab  = region2;
  short* Mb  = Ab + (size_t)B_ * S_ * D_;
  short* WkT = Mb + (size_t)B_ * M_ * D_;
  short* WvT = WkT + (size_t)D_ * P_;
  short* WqT = WvT + (size_t)D_ * P_;
  short* Eb  = region2;   // overlaps the above (all dead before E is written)

  dim3 blk(256);

  const int n4A = B_ * S_ * D_ / 4;
  const int n4M = B_ * M_ * D_ / 4;
  cast_both<<<dim3((n4A + n4M) / 256), blk, 0, stream>>>(input_seq, Ab, n4A, memcells, Mb);
  wtrans_all<<<dim3(16, 16, 10), blk, 0, stream>>>(Wk, Wv, Wq, WkT, WvT, WqT);
  wtrans_wo<<<dim3(16, 128), blk, 0, stream>>>(Wo, WoT);

  proj_kv<true><<<dim3(8, 128), blk, 0, stream>>>(Ab, WkT, WvT, bk, bv, ikb, ivT);
  proj_kv<false><<<dim3(8, 16), blk, 0, stream>>>(Mb, WkT, WvT, bk, bv, mkb, mvb);

  // q projection: MODE 1, z = h
  gemm128<1, 512, 512, 512, 512><<<dim3(4, 16, 8), blk, 0, stream>>>(
      Mb, WqT, bq, qb, 0, (size_t)D_ * P_, 0, nullptr, nullptr, nullptr);

  // eself + zero Ls (before QK's atomics)
  selfscore<<<dim3(64), blk, 0, stream>>>(qb, mkb, eself, Ls);

  // E = exp(scale * q @ ik^T) + fused row-sum; per-batch 2048x2048, K=512
  qk256<16><<<dim3(8, 8, 8), dim3(512), 0, stream>>>(qb, ikb, Eb, Ls);

  // val = normalize(E @ iv + eself*mv), concat layout; per-batch 2048x512,
  // K=2048; BN=128 -> grid 256 blocks (full GPU)
  pv128<32><<<dim3(8, 4, 8), dim3(512), 0, stream>>>(Eb, ivT, valb, Ls, eself, mvb);

  // Wo: split-K=4 partials, then reduce+bias
  gemm128<5, 1024, 512, 4096, 4096><<<dim3(4, 16, 4), blk, 0, stream>>>(
      valb, WoT, nullptr, partial, 1024, 1024,
      (size_t)2048 * 512, nullptr, nullptr, nullptr);
  reduce_wo<<<dim3(1024), blk, 0, stream>>>(partial, bo, out);
}